// Round 9
// baseline (372.691 us; speedup 1.0000x reference)
//
#include <hip/hip_runtime.h>

// MemoryReader: B=4, CK=64, N=8192, M=1024, CV=512. Inputs fp32, output fp32.
// logits s[n,m] = (2*mk.qk - |mk|^2)/8; softmax over n; out = mv @ P.
// R15: PASSED 201us k_main (pinned dataflow: GEMM1 A=Q,B=K-streamed, P via 9KB
//   LDS, GEMM2 = pack8(mv fp32) x P-b128). R16 (drop vmcnt drain at barriers):
//   NEUTRAL — so the stall is raw dep-latency at 2 waves/SIMD (grid 512 = 2
//   blocks/CU is the occupancy cap; VGPR 84 allows 4+). MFMA total work = 68 GF
//   = 27us at peak; HBM 2.9% -> pure latency-bound.
// R17: (a) n-split 2-way, grid 1024 = mt16(16) x cs(8) x b(4) x nh(2), 4
//   blocks/CU = 16 waves/CU; blocks store 64x64 fp32 pacc + 64 pdn partials
//   (no normalize); (b) new k_reduce sums pairs, divides, stores out (~8us);
//   (c) k_prep = LDS-transpose version (EXONERATED by R13/R14 bisect: identical
//   error bits with either prep proved both preps equivalent; bug was k_main's).

typedef unsigned short ushort_t;
typedef unsigned int uint_t;
typedef __attribute__((ext_vector_type(8))) short short8;
typedef __attribute__((ext_vector_type(4))) float floatx4;

#define MFMA16(a, b, c) __builtin_amdgcn_mfma_f32_16x16x32_bf16((a), (b), (c), 0, 0, 0)

// Raw barrier: DS-ordering only; global register loads stay in flight.
#define BARRIER_DS() do {                                          \
    asm volatile("s_waitcnt lgkmcnt(0)" ::: "memory");             \
    __builtin_amdgcn_s_barrier();                                  \
} while (0)

__device__ __forceinline__ ushort_t f2b(float f) {
    uint_t b = __float_as_uint(f);
    b += 0x7FFFu + ((b >> 16) & 1u);   // RNE to bf16
    return (ushort_t)(b >> 16);
}

__device__ __forceinline__ short8 pack8(floatx4 a, floatx4 b) {
    short8 r;
    r[0] = (short)f2b(a[0]); r[1] = (short)f2b(a[1]);
    r[2] = (short)f2b(a[2]); r[3] = (short)f2b(a[3]);
    r[4] = (short)f2b(b[0]); r[5] = (short)f2b(b[1]);
    r[6] = (short)f2b(b[2]); r[7] = (short)f2b(b[3]);
    return r;
}

#define BB 4
#define CK 64
#define NN 8192
#define MM 1024
#define CV 512
#define NH 2          // n-split factor
#define NSTEP_H 64    // 64-token steps per half

// ---- module-scope scratch (fully rewritten every call) ----
__device__ __align__(16) ushort_t g_mkT[BB * NN * CK];     // 4 MiB bf16 mk^T [b][n][c]
__device__ __align__(16) float    g_asq8[BB * NN];         // 128 KiB (sum mk^2)/8
__device__ __align__(16) float    g_pacc[1024 * 64 * 64];  // 16 MiB partial acc
__device__ __align__(16) float    g_pdn[1024 * 64];        // 256 KiB partial denom

// ---------------------------------------------------------------------------
// K0 (LDS-transpose, exonerated): block = (b, 64-n tile). Phase1: thread
// (c=t>>2, seg=t&3) loads 16 contiguous fp32 of row c -> lds_t[n][c]. Phase2:
// thread (n=t>>2, seg) reads 16 contiguous c, f2b, 32B store to g_mkT;
// |a|^2 partial + shfl_xor(1,2) -> g_asq8.
// ---------------------------------------------------------------------------
__global__ __launch_bounds__(256) void k_prep(const float* __restrict__ mk) {
    __shared__ float lds_t[64][68];
    int bx = blockIdx.x;
    int b = bx >> 7;             // 0..3
    int nt = bx & 127;           // 0..127
    int tid = threadIdx.x;
    int cc = tid >> 2, seg = tid & 3;
    const float* src = mk + ((size_t)(b * CK + cc)) * NN + nt * 64 + seg * 16;
#pragma unroll
    for (int g = 0; g < 4; g++) {
        floatx4 v = *(const floatx4*)(src + g * 4);
        lds_t[seg * 16 + g * 4 + 0][cc] = v[0];
        lds_t[seg * 16 + g * 4 + 1][cc] = v[1];
        lds_t[seg * 16 + g * 4 + 2][cc] = v[2];
        lds_t[seg * 16 + g * 4 + 3][cc] = v[3];
    }
    __syncthreads();
    int n = tid >> 2;
    const float* row = &lds_t[n][seg * 16];
    float v[16];
#pragma unroll
    for (int i = 0; i < 16; i++) v[i] = row[i];
    float sq = 0.f;
#pragma unroll
    for (int i = 0; i < 16; i++) sq = fmaf(v[i], v[i], sq);
    sq += __shfl_xor(sq, 1, 64);
    sq += __shfl_xor(sq, 2, 64);
    uint4 q0, q1;
    q0.x = (uint_t)f2b(v[0])  | ((uint_t)f2b(v[1])  << 16);
    q0.y = (uint_t)f2b(v[2])  | ((uint_t)f2b(v[3])  << 16);
    q0.z = (uint_t)f2b(v[4])  | ((uint_t)f2b(v[5])  << 16);
    q0.w = (uint_t)f2b(v[6])  | ((uint_t)f2b(v[7])  << 16);
    q1.x = (uint_t)f2b(v[8])  | ((uint_t)f2b(v[9])  << 16);
    q1.y = (uint_t)f2b(v[10]) | ((uint_t)f2b(v[11]) << 16);
    q1.z = (uint_t)f2b(v[12]) | ((uint_t)f2b(v[13]) << 16);
    q1.w = (uint_t)f2b(v[14]) | ((uint_t)f2b(v[15]) << 16);
    ushort_t* dst = g_mkT + ((size_t)b * NN + nt * 64 + n) * CK + seg * 16;
    *(uint4*)dst = q0;
    *(uint4*)(dst + 8) = q1;
    if (seg == 0) g_asq8[(size_t)b * NN + nt * 64 + n] = sq * 0.125f;
}

// ---------------------------------------------------------------------------
// K1: grid 1024 = mt16(16) x cs(8) x b(4) x nh(2); bx%8 = (b*2+nh)%8 -> each
// XCD streams one (b,nh) slice of g_mkT/mv. Block 256 = 4 waves, 4 blocks/CU.
// Per 64-token step within the half (wave w owns n-strip w*16):
//   GEMM1 (R15-pinned): A=Q regs, B=K per-lane 16B loads -> D[m=quad*4+r][n=l15];
//   p=exp(d/4-asq); f2b -> lds_p[m][n] pitch 72. BARRIER_DS.
//   GEMM2 (R15-pinned): A=pack8(mv fp32 regs), B=P b128 -> acc (c=quad*4+r,
//   m=mt*16+l15), wave owns c-strip w*16. BARRIER_DS.
// Epilogue: dn via shfl+atomicAdd, then STORE pacc (unnormalized) + pdn.
// ---------------------------------------------------------------------------

#define STEP(KC0, KC1, AC, MC0, MC1, MC2, MC3, KN0, KN1, AN, MN0, MN1, MN2, MN3, stepv) do { \
    if ((stepv) + 1 < NSTEP_H) {                                                \
        size_t no = (size_t)((stepv) + 1) * 64;                                 \
        const ushort_t* kp = kbase + no * CK;                                   \
        KN0 = *(const short8*)kp;                                               \
        KN1 = *(const short8*)(kp + 32);                                        \
        AN  = asbase[no];                                                       \
        MN0 = *(const floatx4*)(mvbase + no);                                   \
        MN1 = *(const floatx4*)(mvbase + no + 4);                               \
        MN2 = *(const floatx4*)(mvbase + no + 32);                              \
        MN3 = *(const floatx4*)(mvbase + no + 36);                              \
    }                                                                           \
    _Pragma("unroll")                                                           \
    for (int mt = 0; mt < 4; mt++) {                                            \
        floatx4 d = (floatx4){0.f, 0.f, 0.f, 0.f};                              \
        d = MFMA16(qb0[mt], KC0, d);                                            \
        d = MFMA16(qb1[mt], KC1, d);                                            \
        _Pragma("unroll")                                                       \
        for (int r = 0; r < 4; r++) {                                           \
            float p = __expf(d[r] * 0.25f - AC);                                \
            dpart[mt][r] += p;                                                  \
            lds_p[(mt * 16 + quad * 4 + r) * 72 + w * 16 + l15] = f2b(p);       \
        }                                                                       \
    }                                                                           \
    BARRIER_DS();   /* P stores visible; global prefetch stays in flight */     \
    {                                                                           \
        short8 va0 = pack8(MC0, MC1);                                           \
        short8 va1 = pack8(MC2, MC3);                                           \
        _Pragma("unroll")                                                       \
        for (int mt = 0; mt < 4; mt++) {                                        \
            short8 pb0 = *(const short8*)&lds_p[(mt * 16 + l15) * 72 + quad * 8];        \
            short8 pb1 = *(const short8*)&lds_p[(mt * 16 + l15) * 72 + 32 + quad * 8];   \
            acc[mt] = MFMA16(va0, pb0, acc[mt]);                                \
            acc[mt] = MFMA16(va1, pb1, acc[mt]);                                \
        }                                                                       \
    }                                                                           \
    BARRIER_DS();   /* P consumed before next overwrite */                      \
} while (0)

__global__ __launch_bounds__(256, 4) void k_main(const float* __restrict__ qk,
                                                 const float* __restrict__ mv) {
    __shared__ __align__(16) ushort_t lds_p[64 * 72];   // 9 KiB, P [m_loc][n_loc]
    __shared__ float dn[64];                            // denom per m_loc

    int bx = blockIdx.x;
    int mt16 = bx >> 6;          // 0..15
    int cs = (bx >> 3) & 7;      // 0..7
    int b = (bx >> 1) & 3;       // 0..3
    int nh = bx & 1;             // 0..1   (bx%8 const per (b,nh): XCD grouping)
    int c0 = cs * 64;
    int m0 = mt16 * 64;
    int n0 = nh * (NN / NH);

    int tid = threadIdx.x;
    int w = tid >> 6;
    int lane = tid & 63;
    int quad = lane >> 4;
    int l15 = lane & 15;

    if (tid < 64) dn[tid] = 0.f;   // ordered before epilogue by loop barriers

    // ---- Q fragments: 4 m-tiles x K=64 (A-operand rows m = mt*16 + l15) ----
    short8 qb0[4], qb1[4];
#pragma unroll
    for (int mt = 0; mt < 4; mt++) {
#pragma unroll
        for (int j = 0; j < 8; j++) {
            qb0[mt][j] = (short)f2b(qk[(size_t)(b * CK + quad * 8 + j) * MM + m0 + mt * 16 + l15]);
            qb1[mt][j] = (short)f2b(qk[(size_t)(b * CK + 32 + quad * 8 + j) * MM + m0 + mt * 16 + l15]);
        }
    }

    // ---- per-lane stream bases (n-half base n0 folded in) ----
    const ushort_t* kbase  = g_mkT + ((size_t)b * NN + n0 + w * 16 + l15) * CK + quad * 8;
    const float*    asbase = g_asq8 + (size_t)b * NN + n0 + w * 16 + l15;
    const float*    mvbase = mv + ((size_t)(b * CV + c0 + w * 16 + l15)) * NN + n0 + quad * 8;

    floatx4 acc[4];
#pragma unroll
    for (int i = 0; i < 4; i++) acc[i] = (floatx4){0.f, 0.f, 0.f, 0.f};
    float dpart[4][4];
#pragma unroll
    for (int i = 0; i < 4; i++)
#pragma unroll
        for (int j = 0; j < 4; j++) dpart[i][j] = 0.f;

    // ---- prologue: step-0 operands into set A ----
    short8 kA0, kA1, kB0, kB1;
    floatx4 mA0, mA1, mA2, mA3, mB0, mB1, mB2, mB3;
    float aA, aB;
    kA0 = *(const short8*)kbase;
    kA1 = *(const short8*)(kbase + 32);
    aA  = *asbase;
    mA0 = *(const floatx4*)(mvbase);
    mA1 = *(const floatx4*)(mvbase + 4);
    mA2 = *(const floatx4*)(mvbase + 32);
    mA3 = *(const floatx4*)(mvbase + 36);

    for (int sp = 0; sp < NSTEP_H / 2; sp++) {
        STEP(kA0, kA1, aA, mA0, mA1, mA2, mA3, kB0, kB1, aB, mB0, mB1, mB2, mB3, sp * 2);
        STEP(kB0, kB1, aB, mB0, mB1, mB2, mB3, kA0, kA1, aA, mA0, mA1, mA2, mA3, sp * 2 + 1);
    }

    // ---- epilogue: partial denom (reduce over l15, cross-wave atomicAdd) ----
#pragma unroll
    for (int mt = 0; mt < 4; mt++) {
#pragma unroll
        for (int r = 0; r < 4; r++) {
            float s = dpart[mt][r];
            s += __shfl_xor(s, 1, 64);
            s += __shfl_xor(s, 2, 64);
            s += __shfl_xor(s, 4, 64);
            s += __shfl_xor(s, 8, 64);
            if (l15 == 0) atomicAdd(&dn[mt * 16 + quad * 4 + r], s);
        }
    }
    __syncthreads();

    // ---- store partials (no normalize): pacc[bx][c_loc][m_loc], pdn[bx][m] ----
    float* pa = g_pacc + (size_t)bx * 4096;
#pragma unroll
    for (int mt = 0; mt < 4; mt++) {
#pragma unroll
        for (int r = 0; r < 4; r++)
            pa[(w * 16 + quad * 4 + r) * 64 + mt * 16 + l15] = acc[mt][r];
    }
    if (tid < 64) g_pdn[(size_t)bx * 64 + tid] = dn[tid];
}

// ---------------------------------------------------------------------------
// K2: reduce the NH partials, normalize, store fp32 out.
// grid 512 = mt16(16) x cs(8) x b(4); thread t: row c_loc=t>>2, 16 m as 4xfloat4.
// ---------------------------------------------------------------------------
__global__ __launch_bounds__(256) void k_reduce(float* __restrict__ out) {
    __shared__ float rdm[64];
    int bxr = blockIdx.x;
    int mt16 = bxr >> 5;         // 0..15
    int cs = (bxr >> 2) & 7;     // 0..7
    int b = bxr & 3;             // 0..3
    int tid = threadIdx.x;

    const float* p0 = g_pacc + (size_t)(2 * bxr) * 4096;
    const float* p1 = g_pacc + (size_t)(2 * bxr + 1) * 4096;
    if (tid < 64)
        rdm[tid] = 1.0f / (g_pdn[(size_t)(2 * bxr) * 64 + tid] +
                           g_pdn[(size_t)(2 * bxr + 1) * 64 + tid]);
    __syncthreads();

    int c_loc = tid >> 2;            // 0..63
    int mseg = (tid & 3) * 16;       // 0,16,32,48
    size_t pbase = (size_t)c_loc * 64 + mseg;
    size_t obase = (size_t)(b * CV + cs * 64 + c_loc) * MM + mt16 * 64 + mseg;
#pragma unroll
    for (int g4 = 0; g4 < 4; g4++) {
        floatx4 a = *(const floatx4*)(p0 + pbase + g4 * 4);
        floatx4 bb = *(const floatx4*)(p1 + pbase + g4 * 4);
        floatx4 r;
#pragma unroll
        for (int j = 0; j < 4; j++) r[j] = (a[j] + bb[j]) * rdm[mseg + g4 * 4 + j];
        *(floatx4*)(out + obase + g4 * 4) = r;
    }
}

// ---------------------------------------------------------------------------
// launch — inputs identified BY SIZE.
// ---------------------------------------------------------------------------
extern "C" void kernel_launch(void* const* d_in, const int* in_sizes, int n_in,
                              void* d_out, int out_size, void* d_ws, size_t ws_size,
                              hipStream_t stream) {
    const float* mk = nullptr;   // 2,097,152
    const float* qk = nullptr;   //   262,144
    const float* mv = nullptr;   // 16,777,216
    for (int i = 0; i < n_in; i++) {
        if (in_sizes[i] == BB * CK * NN)      mk = (const float*)d_in[i];
        else if (in_sizes[i] == BB * CK * MM) qk = (const float*)d_in[i];
        else if (in_sizes[i] == BB * CV * NN) mv = (const float*)d_in[i];
    }
    float* out = (float*)d_out;
    (void)d_ws; (void)ws_size; (void)out_size;

    k_prep<<<BB * 128, 256, 0, stream>>>(mk);
    k_main<<<16 * 8 * BB * NH, 256, 0, stream>>>(qk, mv);
    k_reduce<<<16 * 8 * BB, 256, 0, stream>>>(out);
}